// Round 13
// baseline (360.540 us; speedup 1.0000x reference)
//
#include <hip/hip_runtime.h>
#include <hip/hip_bf16.h>
#include <hip/hip_cooperative_groups.h>

namespace cg = cooperative_groups;

// SpiralDeblock: B=8, N_IN=7056, N_UP=28224, SEQ=9, CIN=64, COUT=32
namespace {
constexpr int kB    = 8;
constexpr int kNIn  = 7056;
constexpr int kNUp  = 28224;
constexpr int kSeq  = 9;
constexpr int kCin  = 64;
constexpr int kCout = 32;
constexpr int kE    = 3 * kNUp;              // 84672
constexpr int kMRows = kB * kNUp;            // 225792
constexpr int kTilesPerB = kNUp / 16;        // 1764
constexpr int kWFragN = 18 * 2 * 64 * 8;     // 18432 bf16 (36,864 B)
constexpr int kCap   = 24;                   // bucket capacity
constexpr int kPrepVB = kWFragN / 256 + (kE + 255) / 256;  // 72 + 331 = 403
constexpr int kPoolVB = kNUp / 16 * kB;      // 14112
constexpr int kVlocPerXcd = (kTilesPerB + 7) / 8;          // 221 (8 tiles per vloc)

// ws layout (bytes), 16B-aligned
constexpr size_t kOffPool   = 0;                          // bf16 pooled: 28,901,376
constexpr size_t kOffWfrag  = 28901376;                   // 36,864
constexpr size_t kOffCur    = kOffWfrag + 36864;          // 112,896
constexpr size_t kOffBucket = kOffCur + 112896;           // N_UP*24*8 = 5,419,008
}

typedef __attribute__((ext_vector_type(8))) short short8;
typedef __attribute__((ext_vector_type(4))) float f32x4;

__device__ __forceinline__ unsigned short f32_to_bf16(float f) {  // RNE
    unsigned int u = __float_as_uint(f);
    u += 0x7fffu + ((u >> 16) & 1u);
    return (unsigned short)(u >> 16);
}

// ============================ cooperative mega-kernel ======================
// zero -> {wprep, bucket-fill} -> pool -> gemm with grid.sync() between
// phases. All phases grid-stride -> correct at ANY grid size. Launched at
// 1024 (4/CU) with runtime fallback to 512 (2/CU).
__global__ __launch_bounds__(256, 4) void mega_kernel(
        const float* __restrict__ x, const float* __restrict__ W,
        const float* __restrict__ bias, const int* __restrict__ row,
        const int* __restrict__ col, const float* __restrict__ val,
        const int* __restrict__ indices, float* __restrict__ out,
        unsigned short* __restrict__ poolb, unsigned short* __restrict__ wfrag,
        int* __restrict__ cursor, uint2* __restrict__ bucket) {
    __shared__ short8 Bs[18 * 2 * 64];               // 36,864 B, used in P3
    cg::grid_group grid = cg::this_grid();
    const int t    = threadIdx.x;
    const int bid  = blockIdx.x;
    const int nblk = gridDim.x;

    // ---- P0: zero cursor --------------------------------------------------
    for (int i = bid * 256 + t; i < kNUp; i += nblk * 256) cursor[i] = 0;
    grid.sync();

    // ---- P1: W -> B-fragment order (bf16) + bucket edges -------------------
    for (int vb = bid; vb < kPrepVB; vb += nblk) {
        if (vb < kWFragN / 256) {
            int i  = vb * 256 + t;
            int j  = i & 7;
            int l  = (i >> 3) & 63;
            int ct = (i >> 9) & 1;
            int ks = i >> 10;                        // 0..17
            int k  = ks * 32 + (l >> 4) * 8 + j;
            int o  = ct * 16 + (l & 15);
            wfrag[i] = f32_to_bf16(W[k * kCout + o]);
        } else {
            int e = (vb - kWFragN / 256) * 256 + t;
            if (e < kE) {
                int r = row[e];
                int slot = atomicAdd(&cursor[r], 1);
                if ((unsigned)slot < (unsigned)kCap)
                    bucket[(size_t)r * kCap + slot] =
                        make_uint2((unsigned)col[e], __float_as_uint(val[e]));
            }
        }
    }
    grid.sync();

    // ---- P2: pooled[b,r,c] = sum_edges x[b,col,c]*val, bf16 ----------------
    // vb&7 == bid&7 (stride is a multiple of 8): batch<->XCD affinity kept.
    {
        int c4 = t & 15;
        int tr = t >> 4;
        for (int vb = bid; vb < kPoolVB; vb += nblk) {
            int b = vb & 7;
            int r = (vb >> 3) * 16 + tr;
            int n = min(cursor[r], kCap);
            const uint2* bk = bucket + (size_t)r * kCap;
            const float* xb = x + (size_t)b * kNIn * kCin + (size_t)c4 * 4;
            f32x4 acc = {0.f, 0.f, 0.f, 0.f};
#pragma unroll
            for (int p = 0; p < 4; ++p) {
                if (2 * p < n) {
                    uint4 q = *reinterpret_cast<const uint4*>(bk + 2 * p);
                    unsigned c0 = min(q.x, (unsigned)(kNIn - 1));
                    float    v0 = __uint_as_float(q.y);
                    unsigned c1 = min(q.z, (unsigned)(kNIn - 1));
                    float    v1 = (2 * p + 1 < n) ? __uint_as_float(q.w) : 0.f;
                    f32x4 xv0 = *reinterpret_cast<const f32x4*>(xb + (size_t)c0 * kCin);
                    f32x4 xv1 = *reinterpret_cast<const f32x4*>(xb + (size_t)c1 * kCin);
#pragma unroll
                    for (int j = 0; j < 4; ++j)
                        acc[j] = fmaf(xv1[j], v1, fmaf(xv0[j], v0, acc[j]));
                }
            }
            for (int k = 8; k < n; ++k) {            // rare tail
                uint2 ev = bk[k];
                float v = __uint_as_float(ev.y);
                f32x4 xv = *reinterpret_cast<const f32x4*>(xb + (size_t)ev.x * kCin);
#pragma unroll
                for (int j = 0; j < 4; ++j) acc[j] = fmaf(xv[j], v, acc[j]);
            }
            ushort4 o;
            o.x = f32_to_bf16(acc[0]);
            o.y = f32_to_bf16(acc[1]);
            o.z = f32_to_bf16(acc[2]);
            o.w = f32_to_bf16(acc[3]);
            *reinterpret_cast<ushort4*>(poolb + ((size_t)b * kNUp + r) * kCin + c4 * 4) = o;
        }
    }
    grid.sync();

    // ---- P3: MFMA GEMM (2 M-tiles/wave, per-XCD tile chunks) ---------------
    {
        const short8* wfv = (const short8*)wfrag;
#pragma unroll
        for (int i = 0; i < 9; ++i) Bs[i * 256 + t] = wfv[i * 256 + t];
        __syncthreads();

        int l = t & 63, w = t >> 6, m = l & 15, kg = l >> 4;
        int xcd  = bid & 7;
        int jb   = bid >> 3;
        int nper = nblk >> 3;
        const unsigned short* pb = poolb + (size_t)xcd * kNUp * kCin;
        float bs0 = bias[m];
        float bs1 = bias[16 + m];

        for (int vloc = jb; vloc < kVlocPerXcd; vloc += nper) {
            int tb0 = vloc * 8 + w * 2;              // tile-in-batch of tt=0
            if (tb0 >= kTilesPerB) continue;         // wave-uniform
            int nv = min(2, kTilesPerB - tb0);

            int idxs[2][kSeq];
#pragma unroll
            for (int tt = 0; tt < 2; ++tt) {
                int n = (tb0 + (tt < nv ? tt : 0)) * 16 + m;
#pragma unroll
                for (int s = 0; s < kSeq; ++s) idxs[tt][s] = indices[n * kSeq + s];
            }

            short8 A0[2], A1[2], N0[2], N1[2];
#pragma unroll
            for (int tt = 0; tt < 2; ++tt) {
                const short8* ar = (const short8*)(pb + (size_t)idxs[tt][0] * kCin);
                A0[tt] = ar[kg];
                A1[tt] = ar[4 + kg];
            }
            f32x4 acc0[2], acc1[2];
#pragma unroll
            for (int tt = 0; tt < 2; ++tt) {
                acc0[tt] = (f32x4){0.f, 0.f, 0.f, 0.f};
                acc1[tt] = (f32x4){0.f, 0.f, 0.f, 0.f};
            }
#pragma unroll
            for (int s = 0; s < kSeq; ++s) {
                if (s < kSeq - 1) {                  // prefetch s+1 under MFMA burst
#pragma unroll
                    for (int tt = 0; tt < 2; ++tt) {
                        const short8* ar =
                            (const short8*)(pb + (size_t)idxs[tt][s + 1] * kCin);
                        N0[tt] = ar[kg];
                        N1[tt] = ar[4 + kg];
                    }
                }
                short8 b00 = Bs[(4 * s + 0) * 64 + l];
                short8 b01 = Bs[(4 * s + 1) * 64 + l];
                short8 b10 = Bs[(4 * s + 2) * 64 + l];
                short8 b11 = Bs[(4 * s + 3) * 64 + l];
#pragma unroll
                for (int tt = 0; tt < 2; ++tt) {
                    acc0[tt] = __builtin_amdgcn_mfma_f32_16x16x32_bf16(A0[tt], b00, acc0[tt], 0, 0, 0);
                    acc1[tt] = __builtin_amdgcn_mfma_f32_16x16x32_bf16(A0[tt], b01, acc1[tt], 0, 0, 0);
                    acc0[tt] = __builtin_amdgcn_mfma_f32_16x16x32_bf16(A1[tt], b10, acc0[tt], 0, 0, 0);
                    acc1[tt] = __builtin_amdgcn_mfma_f32_16x16x32_bf16(A1[tt], b11, acc1[tt], 0, 0, 0);
                }
#pragma unroll
                for (int tt = 0; tt < 2; ++tt) { A0[tt] = N0[tt]; A1[tt] = N1[tt]; }
            }
#pragma unroll
            for (int tt = 0; tt < 2; ++tt) {
                if (tt < nv) {
                    int orow0 = (xcd * kTilesPerB + tb0 + tt) * 16 + kg * 4;
#pragma unroll
                    for (int r4 = 0; r4 < 4; ++r4) {
                        size_t orow = (size_t)(orow0 + r4) * kCout;
                        out[orow + m]      = fmaxf(acc0[tt][r4] + bs0, 0.f);
                        out[orow + 16 + m] = fmaxf(acc1[tt][r4] + bs1, 0.f);
                    }
                }
            }
        }
    }
}

// ====================== fallback path (round-9 kernels) ====================
__global__ __launch_bounds__(256) void zero_kernel(int* __restrict__ cursor) {
    int i = blockIdx.x * 256 + threadIdx.x;
    if (i < kNUp) cursor[i] = 0;
}

__global__ __launch_bounds__(256) void prep_kernel(const float* __restrict__ W,
                                                   unsigned short* __restrict__ wfrag,
                                                   const int* __restrict__ row,
                                                   const int* __restrict__ col,
                                                   const float* __restrict__ val,
                                                   int* __restrict__ cursor,
                                                   uint2* __restrict__ bucket) {
    int bid = blockIdx.x;
    if (bid < kWFragN / 256) {
        int i  = bid * 256 + threadIdx.x;
        int j  = i & 7;
        int l  = (i >> 3) & 63;
        int ct = (i >> 9) & 1;
        int ks = i >> 10;
        int k  = ks * 32 + (l >> 4) * 8 + j;
        int o  = ct * 16 + (l & 15);
        wfrag[i] = f32_to_bf16(W[k * kCout + o]);
    } else {
        int e = (bid - kWFragN / 256) * 256 + threadIdx.x;
        if (e >= kE) return;
        int r = row[e];
        int slot = atomicAdd(&cursor[r], 1);
        if ((unsigned)slot < (unsigned)kCap)
            bucket[(size_t)r * kCap + slot] = make_uint2((unsigned)col[e], __float_as_uint(val[e]));
    }
}

__global__ __launch_bounds__(256) void pool_gather(const float* __restrict__ x,
                                                   const int* __restrict__ cursor,
                                                   const uint2* __restrict__ bucket,
                                                   unsigned short* __restrict__ poolb) {
    int t  = threadIdx.x;
    int c4 = t & 15;
    int b  = blockIdx.x & 7;
    int rb = blockIdx.x >> 3;
    int r  = rb * 16 + (t >> 4);
    int n  = min(cursor[r], kCap);
    const uint2* bk = bucket + (size_t)r * kCap;
    const float* xb = x + (size_t)b * kNIn * kCin + (size_t)c4 * 4;

    f32x4 acc = {0.f, 0.f, 0.f, 0.f};
#pragma unroll
    for (int p = 0; p < 4; ++p) {
        if (2 * p < n) {
            uint4 q = *reinterpret_cast<const uint4*>(bk + 2 * p);
            unsigned c0 = min(q.x, (unsigned)(kNIn - 1));
            float    v0 = __uint_as_float(q.y);
            unsigned c1 = min(q.z, (unsigned)(kNIn - 1));
            float    v1 = (2 * p + 1 < n) ? __uint_as_float(q.w) : 0.f;
            f32x4 xv0 = *reinterpret_cast<const f32x4*>(xb + (size_t)c0 * kCin);
            f32x4 xv1 = *reinterpret_cast<const f32x4*>(xb + (size_t)c1 * kCin);
#pragma unroll
            for (int j = 0; j < 4; ++j)
                acc[j] = fmaf(xv1[j], v1, fmaf(xv0[j], v0, acc[j]));
        }
    }
    for (int k = 8; k < n; ++k) {
        uint2 ev = bk[k];
        float v = __uint_as_float(ev.y);
        f32x4 xv = *reinterpret_cast<const f32x4*>(xb + (size_t)ev.x * kCin);
#pragma unroll
        for (int j = 0; j < 4; ++j) acc[j] = fmaf(xv[j], v, acc[j]);
    }
    ushort4 o;
    o.x = f32_to_bf16(acc[0]);
    o.y = f32_to_bf16(acc[1]);
    o.z = f32_to_bf16(acc[2]);
    o.w = f32_to_bf16(acc[3]);
    *reinterpret_cast<ushort4*>(poolb + ((size_t)b * kNUp + r) * kCin + c4 * 4) = o;
}

__global__ __launch_bounds__(256) void gemm_mfma(const unsigned short* __restrict__ poolb,
                                                 const unsigned short* __restrict__ wfrag,
                                                 const float* __restrict__ bias,
                                                 const int* __restrict__ indices,
                                                 float* __restrict__ out) {
    __shared__ short8 Bs[18 * 2 * 64];
    int t = threadIdx.x;
    const short8* wf = (const short8*)wfrag;
#pragma unroll
    for (int i = 0; i < 9; ++i) Bs[i * 256 + t] = wf[i * 256 + t];

    int l = t & 63;
    int w = t >> 6;
    int bid = blockIdx.x;
    int wk = (bid & 7) * (gridDim.x >> 3) + (bid >> 3);  // grid 3528 = 8*441
    int mtile = wk * 4 + w;
    int m  = l & 15;
    int kg = l >> 4;
    int b  = mtile / kTilesPerB;
    int nn = (mtile - b * kTilesPerB) * 16 + m;
    const unsigned short* pb = poolb + (size_t)b * kNUp * kCin;

    int idxs[kSeq];
#pragma unroll
    for (int s = 0; s < kSeq; ++s) idxs[s] = indices[nn * kSeq + s];

    short8 A0[kSeq], A1[kSeq];
#pragma unroll
    for (int s = 0; s < kSeq; ++s) {
        const short8* arow = (const short8*)(pb + (size_t)idxs[s] * kCin);
        A0[s] = arow[kg];
        A1[s] = arow[4 + kg];
    }
    float bs0 = bias[m];
    float bs1 = bias[16 + m];

    __syncthreads();

    f32x4 acc0 = {0.f, 0.f, 0.f, 0.f};
    f32x4 acc1 = {0.f, 0.f, 0.f, 0.f};
#pragma unroll
    for (int s = 0; s < kSeq; ++s) {
        short8 b00 = Bs[(4 * s + 0) * 64 + l];
        short8 b01 = Bs[(4 * s + 1) * 64 + l];
        short8 b10 = Bs[(4 * s + 2) * 64 + l];
        short8 b11 = Bs[(4 * s + 3) * 64 + l];
        acc0 = __builtin_amdgcn_mfma_f32_16x16x32_bf16(A0[s], b00, acc0, 0, 0, 0);
        acc1 = __builtin_amdgcn_mfma_f32_16x16x32_bf16(A0[s], b01, acc1, 0, 0, 0);
        acc0 = __builtin_amdgcn_mfma_f32_16x16x32_bf16(A1[s], b10, acc0, 0, 0, 0);
        acc1 = __builtin_amdgcn_mfma_f32_16x16x32_bf16(A1[s], b11, acc1, 0, 0, 0);
    }

    int orow0 = mtile * 16 + kg * 4;
#pragma unroll
    for (int r = 0; r < 4; ++r) {
        size_t orow = (size_t)(orow0 + r) * kCout;
        out[orow + m]      = fmaxf(acc0[r] + bs0, 0.f);
        out[orow + 16 + m] = fmaxf(acc1[r] + bs1, 0.f);
    }
}

extern "C" void kernel_launch(void* const* d_in, const int* in_sizes, int n_in,
                              void* d_out, int out_size, void* d_ws, size_t ws_size,
                              hipStream_t stream) {
    const float* x    = (const float*)d_in[0];
    const float* val  = (const float*)d_in[1];
    const float* W    = (const float*)d_in[2];
    const float* bias = (const float*)d_in[3];
    const int* row     = (const int*)d_in[4];
    const int* col     = (const int*)d_in[5];
    const int* indices = (const int*)d_in[6];
    float* out = (float*)d_out;

    char* wsb = (char*)d_ws;
    unsigned short* poolb = (unsigned short*)(wsb + kOffPool);
    unsigned short* wfrag = (unsigned short*)(wsb + kOffWfrag);
    int* cursor  = (int*)(wsb + kOffCur);
    uint2* bucket = (uint2*)(wsb + kOffBucket);

    const float* xa = x;  const float* Wa = W;  const float* ba = bias;
    const int* ra = row;  const int* ca = col; const float* va = val;
    const int* ia = indices; float* oa = out;
    unsigned short* pa = poolb; unsigned short* wa = wfrag;
    int* cu = cursor; uint2* bu = bucket;
    void* args[] = {(void*)&xa, (void*)&Wa, (void*)&ba, (void*)&ra,
                    (void*)&ca, (void*)&va, (void*)&ia, (void*)&oa,
                    (void*)&pa, (void*)&wa, (void*)&cu, (void*)&bu};

    // Try cooperative at 4 blocks/CU, then 2 blocks/CU, then multi-kernel.
    hipError_t err = hipLaunchCooperativeKernel(mega_kernel, dim3(1024), dim3(256),
                                                args, 0, stream);
    if (err != hipSuccess)
        err = hipLaunchCooperativeKernel(mega_kernel, dim3(512), dim3(256),
                                         args, 0, stream);
    if (err != hipSuccess) {
        zero_kernel<<<(kNUp + 255) / 256, 256, 0, stream>>>(cursor);
        constexpr int prep_blocks = kWFragN / 256 + (kE + 255) / 256;  // 72 + 331
        prep_kernel<<<prep_blocks, 256, 0, stream>>>(W, wfrag, row, col, val, cursor, bucket);
        pool_gather<<<kNUp / 16 * kB, 256, 0, stream>>>(x, cursor, bucket, poolb);
        gemm_mfma<<<(kMRows / 16) / 4, 256, 0, stream>>>(poolb, wfrag, bias, indices, out);
    }
}

// Round 14
// 112.481 us; speedup vs baseline: 3.2053x; 3.2053x over previous
//
#include <hip/hip_runtime.h>
#include <hip/hip_bf16.h>

// SpiralDeblock: B=8, N_IN=7056, N_UP=28224, SEQ=9, CIN=64, COUT=32
namespace {
constexpr int kB    = 8;
constexpr int kNIn  = 7056;
constexpr int kNUp  = 28224;
constexpr int kSeq  = 9;
constexpr int kCin  = 64;
constexpr int kCout = 32;
constexpr int kE    = 3 * kNUp;          // 84672
constexpr int kMRows = kB * kNUp;        // 225792
constexpr int kTilesPerB = kNUp / 16;    // 1764
constexpr int kWFragN = 18 * 2 * 64 * 8; // 18432 bf16 values (36,864 B)
constexpr int kCap   = 24;               // bucket capacity

// ws layout (bytes), 16B-aligned
constexpr size_t kOffPool   = 0;                          // bf16 pooled: 28,901,376
constexpr size_t kOffWfrag  = 28901376;                   // 36,864
constexpr size_t kOffCur    = kOffWfrag + 36864;          // 112,896
constexpr size_t kOffBucket = kOffCur + 112896;           // N_UP*24*8 = 5,419,008
}

typedef __attribute__((ext_vector_type(8))) short short8;
typedef __attribute__((ext_vector_type(4))) float f32x4;

__device__ __forceinline__ unsigned short f32_to_bf16(float f) {  // RNE
    unsigned int u = __float_as_uint(f);
    u += 0x7fffu + ((u >> 16) & 1u);
    return (unsigned short)(u >> 16);
}

// --- zero cursor (graph-safe) ----------------------------------------------
__global__ __launch_bounds__(256) void zero_kernel(int* __restrict__ cursor) {
    int i = blockIdx.x * 256 + threadIdx.x;
    if (i < kNUp) cursor[i] = 0;
}

// --- merged prep: blocks [0,72) W->fragment transpose; rest bucket edges ----
__global__ __launch_bounds__(256) void prep_kernel(const float* __restrict__ W,
                                                   unsigned short* __restrict__ wfrag,
                                                   const int* __restrict__ row,
                                                   const int* __restrict__ col,
                                                   const float* __restrict__ val,
                                                   int* __restrict__ cursor,
                                                   uint2* __restrict__ bucket) {
    int bid = blockIdx.x;
    if (bid < kWFragN / 256) {
        int i  = bid * 256 + threadIdx.x;
        int j  = i & 7;
        int l  = (i >> 3) & 63;
        int ct = (i >> 9) & 1;
        int ks = i >> 10;                            // 0..17
        int k  = ks * 32 + (l >> 4) * 8 + j;
        int o  = ct * 16 + (l & 15);
        wfrag[i] = f32_to_bf16(W[k * kCout + o]);
    } else {
        int e = (bid - kWFragN / 256) * 256 + threadIdx.x;
        if (e >= kE) return;
        int r = row[e];
        int slot = atomicAdd(&cursor[r], 1);
        if ((unsigned)slot < (unsigned)kCap)
            bucket[(size_t)r * kCap + slot] = make_uint2((unsigned)col[e], __float_as_uint(val[e]));
    }
}

// --- pooled[b,r,c] = sum_{edges of r} x[b,col,c]*val, stored bf16 -----------
// b = blockIdx&7: batch<->XCD affinity (1.8 MB x-slice per XCD L2). 22.2 us (r10).
__global__ __launch_bounds__(256) void pool_gather(const float* __restrict__ x,
                                                   const int* __restrict__ cursor,
                                                   const uint2* __restrict__ bucket,
                                                   unsigned short* __restrict__ poolb) {
    int t  = threadIdx.x;
    int c4 = t & 15;
    int b  = blockIdx.x & 7;
    int rb = blockIdx.x >> 3;
    int r  = rb * 16 + (t >> 4);
    int n  = min(cursor[r], kCap);
    const uint2* bk = bucket + (size_t)r * kCap;
    const float* xb = x + (size_t)b * kNIn * kCin + (size_t)c4 * 4;

    f32x4 acc = {0.f, 0.f, 0.f, 0.f};
#pragma unroll
    for (int p = 0; p < 4; ++p) {
        if (2 * p < n) {
            uint4 q = *reinterpret_cast<const uint4*>(bk + 2 * p);
            unsigned c0 = min(q.x, (unsigned)(kNIn - 1));
            float    v0 = __uint_as_float(q.y);
            unsigned c1 = min(q.z, (unsigned)(kNIn - 1));
            float    v1 = (2 * p + 1 < n) ? __uint_as_float(q.w) : 0.f;
            f32x4 xv0 = *reinterpret_cast<const f32x4*>(xb + (size_t)c0 * kCin);
            f32x4 xv1 = *reinterpret_cast<const f32x4*>(xb + (size_t)c1 * kCin);
#pragma unroll
            for (int j = 0; j < 4; ++j)
                acc[j] = fmaf(xv1[j], v1, fmaf(xv0[j], v0, acc[j]));
        }
    }
    for (int k = 8; k < n; ++k) {                    // rare tail
        uint2 ev = bk[k];
        float v = __uint_as_float(ev.y);
        f32x4 xv = *reinterpret_cast<const f32x4*>(xb + (size_t)ev.x * kCin);
#pragma unroll
        for (int j = 0; j < 4; ++j) acc[j] = fmaf(xv[j], v, acc[j]);
    }
    ushort4 o;
    o.x = f32_to_bf16(acc[0]);
    o.y = f32_to_bf16(acc[1]);
    o.z = f32_to_bf16(acc[2]);
    o.w = f32_to_bf16(acc[3]);
    *reinterpret_cast<ushort4*>(poolb + ((size_t)b * kNUp + r) * kCin + c4 * 4) = o;
}

// --- MFMA GEMM (round-9 config). MEASUREMENT: launched TWICE (idempotent:
// reads poolb/wfrag/indices, writes identical out both times).
// dur_us - 76.3 == this kernel's duration G.
__global__ __launch_bounds__(256) void gemm_mfma(const unsigned short* __restrict__ poolb,
                                                 const unsigned short* __restrict__ wfrag,
                                                 const float* __restrict__ bias,
                                                 const int* __restrict__ indices,
                                                 float* __restrict__ out) {
    __shared__ short8 Bs[18 * 2 * 64];               // 36,864 B
    int t = threadIdx.x;
    const short8* wf = (const short8*)wfrag;
#pragma unroll
    for (int i = 0; i < 9; ++i) Bs[i * 256 + t] = wf[i * 256 + t];

    int l = t & 63;
    int w = t >> 6;
    int bid = blockIdx.x;
    int wk = (bid & 7) * (gridDim.x >> 3) + (bid >> 3);  // grid 3528 = 8*441
    int mtile = wk * 4 + w;
    int m  = l & 15;
    int kg = l >> 4;
    int b  = mtile / kTilesPerB;
    int nn = (mtile - b * kTilesPerB) * 16 + m;
    const unsigned short* pb = poolb + (size_t)b * kNUp * kCin;

    int idxs[kSeq];
#pragma unroll
    for (int s = 0; s < kSeq; ++s) idxs[s] = indices[nn * kSeq + s];

    short8 A0[kSeq], A1[kSeq];
#pragma unroll
    for (int s = 0; s < kSeq; ++s) {
        const short8* arow = (const short8*)(pb + (size_t)idxs[s] * kCin);
        A0[s] = arow[kg];
        A1[s] = arow[4 + kg];
    }
    float bs0 = bias[m];
    float bs1 = bias[16 + m];

    __syncthreads();                                 // Bs ready; A loads drained

    f32x4 acc0 = {0.f, 0.f, 0.f, 0.f};
    f32x4 acc1 = {0.f, 0.f, 0.f, 0.f};
#pragma unroll
    for (int s = 0; s < kSeq; ++s) {
        short8 b00 = Bs[(4 * s + 0) * 64 + l];
        short8 b01 = Bs[(4 * s + 1) * 64 + l];
        short8 b10 = Bs[(4 * s + 2) * 64 + l];
        short8 b11 = Bs[(4 * s + 3) * 64 + l];
        acc0 = __builtin_amdgcn_mfma_f32_16x16x32_bf16(A0[s], b00, acc0, 0, 0, 0);
        acc1 = __builtin_amdgcn_mfma_f32_16x16x32_bf16(A0[s], b01, acc1, 0, 0, 0);
        acc0 = __builtin_amdgcn_mfma_f32_16x16x32_bf16(A1[s], b10, acc0, 0, 0, 0);
        acc1 = __builtin_amdgcn_mfma_f32_16x16x32_bf16(A1[s], b11, acc1, 0, 0, 0);
    }

    int orow0 = mtile * 16 + kg * 4;
#pragma unroll
    for (int r = 0; r < 4; ++r) {
        size_t orow = (size_t)(orow0 + r) * kCout;
        out[orow + m]      = fmaxf(acc0[r] + bs0, 0.f);
        out[orow + 16 + m] = fmaxf(acc1[r] + bs1, 0.f);
    }
}

extern "C" void kernel_launch(void* const* d_in, const int* in_sizes, int n_in,
                              void* d_out, int out_size, void* d_ws, size_t ws_size,
                              hipStream_t stream) {
    const float* x    = (const float*)d_in[0];
    const float* val  = (const float*)d_in[1];
    const float* W    = (const float*)d_in[2];
    const float* bias = (const float*)d_in[3];
    const int* row     = (const int*)d_in[4];
    const int* col     = (const int*)d_in[5];
    const int* indices = (const int*)d_in[6];
    float* out = (float*)d_out;

    char* wsb = (char*)d_ws;
    unsigned short* poolb = (unsigned short*)(wsb + kOffPool);
    unsigned short* wfrag = (unsigned short*)(wsb + kOffWfrag);
    int* cursor  = (int*)(wsb + kOffCur);
    uint2* bucket = (uint2*)(wsb + kOffBucket);

    zero_kernel<<<(kNUp + 255) / 256, 256, 0, stream>>>(cursor);

    constexpr int prep_blocks = kWFragN / 256 + (kE + 255) / 256;  // 72 + 331
    prep_kernel<<<prep_blocks, 256, 0, stream>>>(W, wfrag, row, col, val, cursor, bucket);

    pool_gather<<<kNUp / 16 * kB, 256, 0, stream>>>(x, cursor, bucket, poolb);

    // MEASUREMENT: gemm launched twice (idempotent). dur_us - 76.3 == gemm cost G.
    gemm_mfma<<<(kMRows / 16) / 4, 256, 0, stream>>>(poolb, wfrag, bias, indices, out);
    gemm_mfma<<<(kMRows / 16) / 4, 256, 0, stream>>>(poolb, wfrag, bias, indices, out);
}